// Round 1
// baseline (113.302 us; speedup 1.0000x reference)
//
#include <hip/hip_runtime.h>

// WaveletNet: P/U filters are length-1, so the "circular convolution" is a
// scalar multiply. Pure elementwise lifting recurrence over (even, odd) pairs.
// x: (B, L) fp32 -> z: (B, 2, L/2) fp32, plus scalar log_det=0 appended.

#define BB 256
#define LL 65536
#define HH (LL / 2)        // 32768 pairs per row
#define NSTEPS 4

__global__ __launch_bounds__(256) void wavelet_lift_kernel(
    const float4* __restrict__ x4,   // B*L/4 float4s: (e0,o0,e1,o1)
    const float* __restrict__ P,     // 4 coeffs
    const float* __restrict__ U,     // 4 coeffs
    float* __restrict__ out)         // B*2*H floats, then log_det at [B*L]
{
    const int tid = blockIdx.x * blockDim.x + threadIdx.x;
    // total threads = B*L/4 = 4,194,304; each handles pairs (i, i+1)

    const float p0 = P[0], p1 = P[1], p2 = P[2], p3 = P[3];
    const float u0 = U[0], u1 = U[1], u2 = U[2], u3 = U[3];

    const float4 v = x4[tid];

    // pair 0
    float e = v.x, o = v.y, d, a;
    d = o - p0 * e; a = e + u0 * d; e = a; o = d;
    d = o - p1 * e; a = e + u1 * d; e = a; o = d;
    d = o - p2 * e; a = e + u2 * d; e = a; o = d;
    d = o - p3 * e; a = e + u3 * d; e = a; o = d;
    const float ev0 = e, od0 = o;

    // pair 1
    e = v.z; o = v.w;
    d = o - p0 * e; a = e + u0 * d; e = a; o = d;
    d = o - p1 * e; a = e + u1 * d; e = a; o = d;
    d = o - p2 * e; a = e + u2 * d; e = a; o = d;
    d = o - p3 * e; a = e + u3 * d; e = a; o = d;
    const float ev1 = e, od1 = o;

    // output layout: z[b][0][i] at b*2*H + i ; z[b][1][i] at b*2*H + H + i
    const int b = tid >> 14;              // tid / (H/2)
    const int i = (tid & 16383) << 1;     // pair index within row (even)
    float* rowE = out + (size_t)b * (2 * HH) + i;
    float* rowO = rowE + HH;
    *(float2*)rowE = make_float2(ev0, ev1);
    *(float2*)rowO = make_float2(od0, od1);

    if (tid == 0) {
        out[(size_t)BB * LL] = 0.0f;      // log_det
    }
}

extern "C" void kernel_launch(void* const* d_in, const int* in_sizes, int n_in,
                              void* d_out, int out_size, void* d_ws, size_t ws_size,
                              hipStream_t stream) {
    const float4* x4 = (const float4*)d_in[0];
    const float* P = (const float*)d_in[1];
    const float* U = (const float*)d_in[2];
    float* out = (float*)d_out;

    const int total_threads = BB * LL / 4;   // 4,194,304
    const int block = 256;
    const int grid = total_threads / block;  // 16384

    wavelet_lift_kernel<<<grid, block, 0, stream>>>(x4, P, U, out);
}